// Round 8
// baseline (212.321 us; speedup 1.0000x reference)
//
#include <hip/hip_runtime.h>
#include <hip/hip_bf16.h>

#define B_SZ 8192
#define S_DIM 512
#define H_DIM 1024
#define E_DIM 256
#define A_DIM 32

typedef __attribute__((ext_vector_type(4))) float f32x4;
typedef __attribute__((ext_vector_type(8))) __bf16 bf16x8;

using as1_void = __attribute__((address_space(1))) void;
using as3_void = __attribute__((address_space(3))) void;

#define WAITV(N) asm volatile("s_waitcnt vmcnt(" #N ")" ::: "memory")

__device__ __forceinline__ unsigned short f2bfu(float f) {
  unsigned u = __builtin_bit_cast(unsigned, f);
  unsigned r = (u + 0x7FFFu + ((u >> 16) & 1u)) >> 16;
  return (unsigned short)r;
}
__device__ __forceinline__ float bf2f(unsigned short x) {
  unsigned u = ((unsigned)x) << 16;
  return __builtin_bit_cast(float, u);
}

// 16-lane xor-butterfly sum via DPP (VALU pipe, no LDS traffic).
__device__ __forceinline__ float row16_sum(float s) {
  float t;
  t = __builtin_bit_cast(float, __builtin_amdgcn_update_dpp(
          0, __builtin_bit_cast(int, s), 0xB1, 0xF, 0xF, true));
  s += t;
  t = __builtin_bit_cast(float, __builtin_amdgcn_update_dpp(
          0, __builtin_bit_cast(int, s), 0x4E, 0xF, 0xF, true));
  s += t;
  t = __builtin_bit_cast(float, __builtin_amdgcn_update_dpp(
          0, __builtin_bit_cast(int, s), 0x141, 0xF, 0xF, true));
  s += t;
  t = __builtin_bit_cast(float, __builtin_amdgcn_update_dpp(
          0, __builtin_bit_cast(int, s), 0x140, 0xF, 0xF, true));
  s += t;
  return s;
}

// elementwise f32 -> bf16 (n multiple of 4)
__global__ void conv_kernel(const float* __restrict__ in, unsigned short* __restrict__ out, int n) {
  int i = blockIdx.x * blockDim.x + threadIdx.x;
  int idx = i * 4;
  if (idx >= n) return;
  const float4 v = *(const float4*)(in + idx);
  ushort4 o;
  o.x = f2bfu(v.x); o.y = f2bfu(v.y); o.z = f2bfu(v.z); o.w = f2bfu(v.w);
  *(ushort4*)(out + idx) = o;
}

// transpose+convert: in [R][C] f32 -> out [C'][R] bf16 where C' = perm(C).
// PERM=1 (for hw1_w2): col n = a*256+e  ->  row n' = e*32+a.
template <int PERM>
__global__ void tconv_kernel(const float* __restrict__ in, unsigned short* __restrict__ out,
                             int R, int C) {
  __shared__ float t[32][33];
  int tx = threadIdx.x, ty = threadIdx.y;
  int c0 = blockIdx.x * 32, r0 = blockIdx.y * 32;
#pragma unroll
  for (int i = 0; i < 4; ++i) {
    int r = r0 + ty + i * 8;
    t[ty + i * 8][tx] = in[(size_t)r * C + c0 + tx];
  }
  __syncthreads();
#pragma unroll
  for (int i = 0; i < 4; ++i) {
    int c = c0 + ty + i * 8;
    size_t co = PERM ? (size_t)(((c & 255) << 5) + (c >> 8)) : (size_t)c;
    out[co * R + r0 + tx] = f2bfu(t[tx][ty + i * 8]);
  }
}

// permuted bias: out[n'] = in[a*256+e], n' = e*32+a
__global__ void bperm_kernel(const float* __restrict__ in, float* __restrict__ out) {
  int n = blockIdx.x * 256 + threadIdx.x;
  out[n] = in[((n & 31) << 8) + (n >> 5)];
}

// concat 4 bias vectors: [0,1024)=b0, [1024,2048)=b1, [2048,2304)=b2, [2304,2560)=b3
__global__ void bcat_kernel(const float* __restrict__ b0, const float* __restrict__ b1,
                            const float* __restrict__ b2, const float* __restrict__ b3,
                            float* __restrict__ out) {
  int i = blockIdx.x * 256 + threadIdx.x;
  float v;
  if (i < 1024) v = b0[i];
  else if (i < 2048) v = b1[i - 1024];
  else if (i < 2304) v = b2[i - 2048];
  else v = b3[i - 2304];
  out[i] = v;
}

// ---------------- 128x128 2-phase GEMM (m97 structure), A-stride generalized -------------
template <int ACT>
__global__ void gemm_bt(const unsigned short* __restrict__ A, int Astr,
                        const unsigned short* __restrict__ BT,
                        const float* __restrict__ bias, void* __restrict__ Cp,
                        int M, int N, int K) {
  __shared__ unsigned short As[128 * 64];
  __shared__ unsigned short Bs[128 * 64];
  const int tid = threadIdx.x;
  const int w = tid >> 6, l = tid & 63;
  const int wr = w >> 1, wc = w & 1;
  const int row0 = blockIdx.y * 128, col0 = blockIdx.x * 128;
  f32x4 acc[4][4] = {};
  for (int k0 = 0; k0 < K; k0 += 64) {
    __syncthreads();
#pragma unroll
    for (int i = 0; i < 4; ++i) {
      int cbase = i * 256 + w * 64;
      int c = cbase + l;
      int r = c >> 3, kc = c & 7;
      const unsigned short* src = A + (size_t)(row0 + r) * Astr + (k0 + kc * 8);
      __builtin_amdgcn_global_load_lds((const as1_void*)src, (as3_void*)&As[cbase * 8], 16, 0, 0);
    }
#pragma unroll
    for (int i = 0; i < 4; ++i) {
      int cbase = i * 256 + w * 64;
      int c = cbase + l;
      int r = c >> 3, kc = c & 7;
      const unsigned short* src = BT + (size_t)(col0 + r) * K + (k0 + kc * 8);
      __builtin_amdgcn_global_load_lds((const as1_void*)src, (as3_void*)&Bs[cbase * 8], 16, 0, 0);
    }
    __syncthreads();
#pragma unroll
    for (int kk = 0; kk < 2; ++kk) {
      bf16x8 af[4], bfr[4];
#pragma unroll
      for (int i = 0; i < 4; ++i)
        af[i] = *(const bf16x8*)&As[(wr * 64 + i * 16 + (l & 15)) * 64 + kk * 32 + (l >> 4) * 8];
#pragma unroll
      for (int j = 0; j < 4; ++j)
        bfr[j] = *(const bf16x8*)&Bs[(wc * 64 + j * 16 + (l & 15)) * 64 + kk * 32 + (l >> 4) * 8];
#pragma unroll
      for (int i = 0; i < 4; ++i)
#pragma unroll
        for (int j = 0; j < 4; ++j)
          acc[i][j] = __builtin_amdgcn_mfma_f32_16x16x32_bf16(af[i], bfr[j], acc[i][j], 0, 0, 0);
    }
  }
#pragma unroll
  for (int i = 0; i < 4; ++i)
#pragma unroll
    for (int j = 0; j < 4; ++j)
#pragma unroll
      for (int t = 0; t < 4; ++t) {
        int r = row0 + wr * 64 + i * 16 + (l >> 4) * 4 + t;
        int c = col0 + wc * 64 + j * 16 + (l & 15);
        float v = acc[i][j][t] + bias[c];
        if (ACT == 1) v = fmaxf(v, 0.0f);
        if (ACT == 2) v = fabsf(v);
        if (ACT == 0)
          ((float*)Cp)[(size_t)r * N + c] = v;
        else
          ((unsigned short*)Cp)[(size_t)r * N + c] = f2bfu(v);
      }
}

// ---------------- 256x256 deep-prefetch GEMM, two epilogues ------------------------------
// Snake loop: p0 q(0,0)[lda0,ldb0], p1 q(0,1)[ldb1], p2 q(1,1)[lda1], p3 q(1,0)[regs only].
// Stage slots: p0: B0(t+1)+B1(t+1); p1: A1(t+1); p2: A0(t+2) (1.5 tiles ahead).
// Waits: p0 vmcnt(8), p1 vmcnt(8), p2 none, p3 vmcnt(6) — every load flies >=3 phases
// (>=1100 cyc > 900-cyc HBM miss). FIFO trace (steady, per-wave loads):
//   entering p0(t): [B1(t),A1(t),A0(t+1)]=6; p0 +4 ->10, wait 8 drains B1(t) (read p1)
//   p1 +2 ->10, wait 8 drains A1(t) (read p2); p2 +2 ->10; p3 wait 6 drains A0(t+1),B0(t+1)
//   (read p0(t+1)). Tails: t=NT-2 p3 -> vmcnt(4); t=NT-1: p0 vmcnt(2), p1 vmcnt(0).
// Overwrite safety: every stage lands >=1 barrier after its region's last ds_read.
// EPI=0: bf16 out, bias+relu except [nr_lo,nr_hi). EPI=1: agent contraction (reg-hoisted
// qs/bias, DPP butterfly) -> f32 hid.
template <int EPI>
__global__ __launch_bounds__(512, 2) void gemm256(
    const unsigned short* __restrict__ A, int Astr, const unsigned short* __restrict__ BT,
    const float* __restrict__ bias, const float* __restrict__ qs,
    void* __restrict__ outp, int Cstr, int M, int N, int K, int nr_lo, int nr_hi) {
  __shared__ __align__(16) char smem[131072];  // A: [0,64K) B: [64K,128K); 2 buf x 2 half x 16KB
  const int tid = threadIdx.x;
  const int w = tid >> 6, l = tid & 63;
  const int wrow = w >> 2, wcol = w & 3;
  const int row0 = blockIdx.y * 256, col0 = blockIdx.x * 256;
  const int NT = K >> 6;  // K-tiles; requires K%64==0, NT>=2

  bf16x8 af[8];
  bf16x8 b0r[4], b1r[4];
  f32x4 acc[2][2][4][2] = {};

  auto stage = [&](int mat, int h, int t, int buf) {
    const unsigned short* base = mat ? BT : A;
    const int rbase = (mat ? col0 : row0) + h * 128;
    const int str = mat ? K : Astr;
    const int k0 = t * 64;
    char* region = smem + mat * 65536 + buf * 32768 + h * 16384;
#pragma unroll
    for (int j = 0; j < 2; ++j) {
      const int c = j * 512 + w * 64 + l;
      const int r = c >> 3, kc = c & 7;
      const unsigned short* src =
          base + (size_t)(rbase + r) * str + (k0 + ((kc ^ (r & 7)) << 3));
      __builtin_amdgcn_global_load_lds((const as1_void*)src,
                                       (as3_void*)(region + (j * 512 + w * 64) * 16), 16, 0, 0);
    }
  };
  auto lda = [&](int qa, int buf) {
    const char* region = smem + buf * 32768 + qa * 16384;
#pragma unroll
    for (int i = 0; i < 4; ++i) {
      const int r = wrow * 64 + i * 16 + (l & 15);
#pragma unroll
      for (int kk = 0; kk < 2; ++kk) {
        const int kc = kk * 4 + (l >> 4);
        af[i * 2 + kk] = *(const bf16x8*)(region + r * 128 + ((kc ^ (r & 7)) << 4));
      }
    }
  };
  auto ldb = [&](bf16x8 (&br)[4], int qb, int buf) {
    const char* region = smem + 65536 + buf * 32768 + qb * 16384;
#pragma unroll
    for (int j = 0; j < 2; ++j) {
      const int r = wcol * 32 + j * 16 + (l & 15);
#pragma unroll
      for (int kk = 0; kk < 2; ++kk) {
        const int kc = kk * 4 + (l >> 4);
        br[j * 2 + kk] = *(const bf16x8*)(region + r * 128 + ((kc ^ (r & 7)) << 4));
      }
    }
  };
  auto mf = [&](f32x4 (&ac)[4][2], bf16x8 (&br)[4]) {
    __builtin_amdgcn_s_setprio(1);
#pragma unroll
    for (int i = 0; i < 4; ++i)
#pragma unroll
      for (int j = 0; j < 2; ++j)
#pragma unroll
        for (int kk = 0; kk < 2; ++kk)
          ac[i][j] = __builtin_amdgcn_mfma_f32_16x16x32_bf16(af[i * 2 + kk], br[j * 2 + kk],
                                                             ac[i][j], 0, 0, 0);
    __builtin_amdgcn_s_setprio(0);
  };
  auto bar = [&]() {
    asm volatile("" ::: "memory");
    __builtin_amdgcn_s_barrier();
    asm volatile("" ::: "memory");
  };

  // prologue: tile0 (A0,B0,B1,A1) -> buf0, A0(1) -> buf1; drain A0(0),B0(0).
  // Leaves queue = [B1(0),A1(0),A0(1)] = 6 = steady-state p0-entry invariant.
  stage(0, 0, 0, 0); stage(1, 0, 0, 0); stage(1, 1, 0, 0); stage(0, 1, 0, 0);
  stage(0, 0, 1, 1);
  WAITV(6);
  bar();

  for (int t = 0; t < NT; ++t) {
    const int buf = t & 1, nbuf = buf ^ 1;
    const bool s1 = (t + 1 < NT), s2 = (t + 2 < NT);
    // p0: q(0,0); stage B0(t+1), B1(t+1)
    lda(0, buf); ldb(b0r, 0, buf);
    if (s1) {
      stage(1, 0, t + 1, nbuf); stage(1, 1, t + 1, nbuf);
      WAITV(8);
    } else {
      WAITV(2);
    }
    bar();
    mf(acc[0][0], b0r);
    // p1: q(0,1); stage A1(t+1)
    ldb(b1r, 1, buf);
    if (s1) {
      stage(0, 1, t + 1, nbuf);
      WAITV(8);
    } else {
      WAITV(0);
    }
    bar();
    mf(acc[0][1], b1r);
    // p2: q(1,1); stage A0(t+2) into current buf (A0(t) last read at p0 — 2 barriers ago)
    lda(1, buf);
    if (s2) stage(0, 0, t + 2, buf);
    bar();
    mf(acc[1][1], b1r);
    // p3: q(1,0); pure MFMA phase (B0 frags held in b0r)
    if (s2) { WAITV(6); }
    else if (s1) { WAITV(4); }
    bar();
    mf(acc[1][0], b0r);
  }

  if constexpr (EPI == 0) {
    // store epilogue: bf16 out with bias + relu except [nr_lo, nr_hi)
#pragma unroll
    for (int qa = 0; qa < 2; ++qa)
#pragma unroll
      for (int qb = 0; qb < 2; ++qb)
#pragma unroll
        for (int i = 0; i < 4; ++i)
#pragma unroll
          for (int j = 0; j < 2; ++j)
#pragma unroll
            for (int tt = 0; tt < 4; ++tt) {
              const int r = row0 + qa * 128 + wrow * 64 + i * 16 + (l >> 4) * 4 + tt;
              const int cc = col0 + qb * 128 + wcol * 32 + j * 16 + (l & 15);
              float v = acc[qa][qb][i][j][tt] + bias[cc];
              if (!(cc >= nr_lo && cc < nr_hi)) v = fmaxf(v, 0.0f);
              ((unsigned short*)outp)[(size_t)r * Cstr + cc] = f2bfu(v);
            }
  } else {
    // agent-contraction epilogue: hoist qs/bias to registers (68 independent loads),
    // then pure VALU + DPP butterfly; write hid[r][e] f32.
    float qv[2][4][4][2];
    float bp[2][2];
#pragma unroll
    for (int qa = 0; qa < 2; ++qa)
#pragma unroll
      for (int i = 0; i < 4; ++i)
#pragma unroll
        for (int tt = 0; tt < 4; ++tt)
#pragma unroll
          for (int j = 0; j < 2; ++j)
            qv[qa][i][tt][j] =
                qs[(size_t)(row0 + qa * 128 + wrow * 64 + i * 16 + (l >> 4) * 4 + tt) * A_DIM +
                   j * 16 + (l & 15)];
#pragma unroll
    for (int qb = 0; qb < 2; ++qb)
#pragma unroll
      for (int j = 0; j < 2; ++j)
        bp[qb][j] = bias[col0 + qb * 128 + wcol * 32 + j * 16 + (l & 15)];
    float* hid = (float*)outp;
#pragma unroll
    for (int qa = 0; qa < 2; ++qa)
#pragma unroll
      for (int qb = 0; qb < 2; ++qb) {
        const int e = (col0 >> 5) + qb * 4 + wcol;
#pragma unroll
        for (int i = 0; i < 4; ++i)
#pragma unroll
          for (int tt = 0; tt < 4; ++tt) {
            const int r = row0 + qa * 128 + wrow * 64 + i * 16 + (l >> 4) * 4 + tt;
            float s = 0.0f;
#pragma unroll
            for (int j = 0; j < 2; ++j)
              s = fmaf(qv[qa][i][tt][j], fabsf(acc[qa][qb][i][j][tt] + bp[qb][j]), s);
            s = row16_sum(s);
            if ((l & 15) == 0) hid[(size_t)r * Cstr + e] = s;
          }
      }
  }
}

// tiny final pass: out[b] = sum_e elu(hid+b1)*wf + sum_e vh*vw2 + vb2
__global__ void final2_kernel(const float* __restrict__ hid, const unsigned short* __restrict__ b1p,
                              const unsigned short* __restrict__ vhp, int ostr,
                              const unsigned short* __restrict__ wf,
                              const float* __restrict__ vw2, const float* __restrict__ vb2,
                              float* __restrict__ out) {
  const int tid = threadIdx.x;  // e
  const int b = blockIdx.x;
  float h = hid[(size_t)b * E_DIM + tid] + bf2f(b1p[(size_t)b * ostr + tid]);
  float hidden = h > 0.0f ? h : (expf(h) - 1.0f);  // elu
  float s = hidden * bf2f(wf[(size_t)b * E_DIM + tid]) +
            bf2f(vhp[(size_t)b * ostr + tid]) * vw2[tid];
  __shared__ float red[4];
#pragma unroll
  for (int o = 32; o > 0; o >>= 1) s += __shfl_down(s, o, 64);
  if ((tid & 63) == 0) red[tid >> 6] = s;
  __syncthreads();
  if (tid == 0) out[b] = red[0] + red[1] + red[2] + red[3] + vb2[0];
}

extern "C" void kernel_launch(void* const* d_in, const int* in_sizes, int n_in,
                              void* d_out, int out_size, void* d_ws, size_t ws_size,
                              hipStream_t stream) {
  const float* agent_qs = (const float*)d_in[0];
  const float* states = (const float*)d_in[1];
  const float* hw1_w1 = (const float*)d_in[2];
  const float* hw1_b1 = (const float*)d_in[3];
  const float* hw1_w2 = (const float*)d_in[4];
  const float* hw1_b2 = (const float*)d_in[5];
  const float* hb1_w = (const float*)d_in[6];
  const float* hb1_b = (const float*)d_in[7];
  const float* hwf_w1 = (const float*)d_in[8];
  const float* hwf_b1 = (const float*)d_in[9];
  const float* hwf_w2 = (const float*)d_in[10];
  const float* hwf_b2 = (const float*)d_in[11];
  const float* v_w1 = (const float*)d_in[12];
  const float* v_b1 = (const float*)d_in[13];
  const float* v_w2 = (const float*)d_in[14];
  const float* v_b2 = (const float*)d_in[15];
  float* out = (float*)d_out;

  size_t off = 0;
  char* ws = (char*)d_ws;
  auto carve = [&](size_t bytes) -> void* {
    void* p = ws + off;
    off = (off + bytes + 255) & ~(size_t)255;
    return p;
  };
  const int NCAT = 2560;  // 1024 h1 | 1024 hf | 256 b1 | 256 vh
  unsigned short* st_bf = (unsigned short*)carve((size_t)B_SZ * S_DIM * 2);
  unsigned short* wcat = (unsigned short*)carve((size_t)NCAT * S_DIM * 2);
  unsigned short* w12T = (unsigned short*)carve((size_t)8192 * H_DIM * 2);
  unsigned short* wf2T = (unsigned short*)carve((size_t)E_DIM * H_DIM * 2);
  float* bcatp = (float*)carve((size_t)NCAT * 4);
  float* bias_p = (float*)carve((size_t)8192 * 4);
  unsigned short* ocat = (unsigned short*)carve((size_t)B_SZ * NCAT * 2);
  unsigned short* wfb = (unsigned short*)carve((size_t)B_SZ * E_DIM * 2);
  float* hid = (float*)carve((size_t)B_SZ * E_DIM * 4);

  // converts: states -> bf16; weights -> B^T bf16 (wcat = 4 stacked K=512 weights;
  // w12T column-permuted n'=e*32+a for the fused agent contraction)
  conv_kernel<<<(B_SZ * S_DIM / 4 + 255) / 256, 256, 0, stream>>>(states, st_bf, B_SZ * S_DIM);
  dim3 tb(32, 8);
  tconv_kernel<0><<<dim3(H_DIM / 32, S_DIM / 32), tb, 0, stream>>>(hw1_w1, wcat, S_DIM, H_DIM);
  tconv_kernel<0><<<dim3(H_DIM / 32, S_DIM / 32), tb, 0, stream>>>(hwf_w1, wcat + (size_t)1024 * S_DIM, S_DIM, H_DIM);
  tconv_kernel<0><<<dim3(E_DIM / 32, S_DIM / 32), tb, 0, stream>>>(hb1_w, wcat + (size_t)2048 * S_DIM, S_DIM, E_DIM);
  tconv_kernel<0><<<dim3(E_DIM / 32, S_DIM / 32), tb, 0, stream>>>(v_w1, wcat + (size_t)2304 * S_DIM, S_DIM, E_DIM);
  tconv_kernel<1><<<dim3(8192 / 32, H_DIM / 32), tb, 0, stream>>>(hw1_w2, w12T, H_DIM, 8192);
  tconv_kernel<0><<<dim3(E_DIM / 32, H_DIM / 32), tb, 0, stream>>>(hwf_w2, wf2T, H_DIM, E_DIM);
  bcat_kernel<<<NCAT / 256, 256, 0, stream>>>(hw1_b1, hwf_b1, hb1_b, v_b1, bcatp);
  bperm_kernel<<<32, 256, 0, stream>>>(hw1_b2, bias_p);

  // one consolidated K=512 GEMM: ocat[8192][2560] = act(st @ wcat^T + bcat)
  // relu everywhere except b1 range [2048,2304)
  gemm256<0><<<dim3(NCAT / 256, B_SZ / 256), 512, 0, stream>>>(
      st_bf, S_DIM, wcat, bcatp, nullptr, ocat, NCAT, B_SZ, NCAT, S_DIM, 2048, 2304);

  // w_final = |hf @ hwf_w2 + b|  (A = ocat cols [1024,2048), strided)
  gemm_bt<2><<<dim3(E_DIM / 128, B_SZ / 128), 256, 0, stream>>>(
      ocat + 1024, NCAT, wf2T, hwf_b2, wfb, B_SZ, E_DIM, H_DIM);

  // big GEMM with fused |.| + agent contraction -> hid (A = ocat cols [0,1024), strided)
  gemm256<1><<<dim3(8192 / 256, B_SZ / 256), 512, 0, stream>>>(
      ocat, NCAT, w12T, bias_p, agent_qs, hid, E_DIM, B_SZ, 8192, H_DIM, 0, 0);

  // tiny epilogue
  final2_kernel<<<B_SZ, 256, 0, stream>>>(hid, ocat + 2048, ocat + 2304, NCAT, wfb, v_w2, v_b2, out);
}

// Round 9
// 190.476 us; speedup vs baseline: 1.1147x; 1.1147x over previous
//
#include <hip/hip_runtime.h>
#include <hip/hip_bf16.h>

#define B_SZ 8192
#define S_DIM 512
#define H_DIM 1024
#define E_DIM 256
#define A_DIM 32

typedef __attribute__((ext_vector_type(4))) float f32x4;
typedef __attribute__((ext_vector_type(8))) __bf16 bf16x8;

using as1_void = __attribute__((address_space(1))) void;
using as3_void = __attribute__((address_space(3))) void;

#define WAITV(N) asm volatile("s_waitcnt vmcnt(" #N ")" ::: "memory")

__device__ __forceinline__ unsigned short f2bfu(float f) {
  unsigned u = __builtin_bit_cast(unsigned, f);
  unsigned r = (u + 0x7FFFu + ((u >> 16) & 1u)) >> 16;
  return (unsigned short)r;
}
__device__ __forceinline__ float bf2f(unsigned short x) {
  unsigned u = ((unsigned)x) << 16;
  return __builtin_bit_cast(float, u);
}

// 16-lane xor-butterfly sum via DPP (VALU pipe, no LDS traffic).
__device__ __forceinline__ float row16_sum(float s) {
  float t;
  t = __builtin_bit_cast(float, __builtin_amdgcn_update_dpp(
          0, __builtin_bit_cast(int, s), 0xB1, 0xF, 0xF, true));
  s += t;
  t = __builtin_bit_cast(float, __builtin_amdgcn_update_dpp(
          0, __builtin_bit_cast(int, s), 0x4E, 0xF, 0xF, true));
  s += t;
  t = __builtin_bit_cast(float, __builtin_amdgcn_update_dpp(
          0, __builtin_bit_cast(int, s), 0x141, 0xF, 0xF, true));
  s += t;
  t = __builtin_bit_cast(float, __builtin_amdgcn_update_dpp(
          0, __builtin_bit_cast(int, s), 0x140, 0xF, 0xF, true));
  s += t;
  return s;
}

// ---------------- single mega prep kernel: all converts/transposes/bias packs ------------
// Block ranges (256 threads each):
//   [0,4096)        conv: states f32 -> st_bf (1024 elems/block)
//   [4096,4608)     tconv hw1_w1 -> wcat[0:1024]        R=512  C=1024
//   [4608,5120)     tconv hwf_w1 -> wcat[1024:2048]     R=512  C=1024
//   [5120,5248)     tconv hb1_w  -> wcat[2048:2304]     R=512  C=256
//   [5248,5376)     tconv v_w1   -> wcat[2304:2560]     R=512  C=256
//   [5376,13568)    tconv hw1_w2 -> w12T (PERM n'=e*32+a) R=1024 C=8192
//   [13568,13824)   tconv hwf_w2 -> wf2T                R=1024 C=256
//   [13824,13834)   bcat: bcatp[2560]
//   [13834,13866)   bperm: bias_p[8192]
#define PREP_BLOCKS 13866
__global__ void prep_kernel(const float* __restrict__ states, const float* __restrict__ hw1_w1,
                            const float* __restrict__ hwf_w1, const float* __restrict__ hb1_w,
                            const float* __restrict__ v_w1, const float* __restrict__ hw1_w2,
                            const float* __restrict__ hwf_w2, const float* __restrict__ hw1_b1,
                            const float* __restrict__ hwf_b1, const float* __restrict__ hb1_b,
                            const float* __restrict__ v_b1, const float* __restrict__ hw1_b2,
                            unsigned short* __restrict__ st_bf, unsigned short* __restrict__ wcat,
                            unsigned short* __restrict__ w12T, unsigned short* __restrict__ wf2T,
                            float* __restrict__ bcatp, float* __restrict__ bias_p) {
  __shared__ float t[32][33];
  const int tid = threadIdx.x;
  int b = blockIdx.x;
  if (b < 4096) {  // conv
    int idx = b * 1024 + tid * 4;
    const float4 v = *(const float4*)(states + idx);
    ushort4 o;
    o.x = f2bfu(v.x); o.y = f2bfu(v.y); o.z = f2bfu(v.z); o.w = f2bfu(v.w);
    *(ushort4*)(st_bf + idx) = o;
    return;
  }
  b -= 4096;
  if (b >= 9728) {  // bcat / bperm
    b -= 9728;
    if (b < 10) {
      int i = b * 256 + tid;
      if (i < 2560) {
        float v;
        if (i < 1024) v = hw1_b1[i];
        else if (i < 2048) v = hwf_b1[i - 1024];
        else if (i < 2304) v = hb1_b[i - 2048];
        else v = v_b1[i - 2304];
        bcatp[i] = v;
      }
    } else {
      int n = (b - 10) * 256 + tid;
      bias_p[n] = hw1_b2[((n & 31) << 8) + (n >> 5)];
    }
    return;
  }
  // transpose jobs
  const float* src;
  unsigned short* dst;
  int R, C, tile;
  bool perm = false;
  if (b < 512) { src = hw1_w1; dst = wcat; R = 512; C = 1024; tile = b; }
  else if (b < 1024) { src = hwf_w1; dst = wcat + (size_t)1024 * 512; R = 512; C = 1024; tile = b - 512; }
  else if (b < 1152) { src = hb1_w; dst = wcat + (size_t)2048 * 512; R = 512; C = 256; tile = b - 1024; }
  else if (b < 1280) { src = v_w1; dst = wcat + (size_t)2304 * 512; R = 512; C = 256; tile = b - 1152; }
  else if (b < 9472) { src = hw1_w2; dst = w12T; R = 1024; C = 8192; tile = b - 1280; perm = true; }
  else { src = hwf_w2; dst = wf2T; R = 1024; C = 256; tile = b - 9472; }
  const int tpc = C >> 5;
  const int c0 = (tile % tpc) * 32, r0 = (tile / tpc) * 32;
  const int tx = tid & 31, ty = tid >> 5;
#pragma unroll
  for (int i = 0; i < 4; ++i) {
    int r = r0 + ty + i * 8;
    t[ty + i * 8][tx] = src[(size_t)r * C + c0 + tx];
  }
  __syncthreads();
#pragma unroll
  for (int i = 0; i < 4; ++i) {
    int c = c0 + ty + i * 8;
    size_t co = perm ? (size_t)(((c & 255) << 5) + (c >> 8)) : (size_t)c;
    dst[co * R + r0 + tx] = f2bfu(t[tx][ty + i * 8]);
  }
}

// ---------------- 128x128 2-phase GEMM (m97 structure), A-stride + relu-exempt range -----
// ACT: 1 relu (except cols [nr_lo,nr_hi)) -> bf16; 2 abs -> bf16.
template <int ACT>
__global__ void gemm_bt(const unsigned short* __restrict__ A, int Astr,
                        const unsigned short* __restrict__ BT,
                        const float* __restrict__ bias, void* __restrict__ Cp,
                        int M, int N, int K, int nr_lo, int nr_hi) {
  __shared__ unsigned short As[128 * 64];
  __shared__ unsigned short Bs[128 * 64];
  const int tid = threadIdx.x;
  const int w = tid >> 6, l = tid & 63;
  const int wr = w >> 1, wc = w & 1;
  const int row0 = blockIdx.y * 128, col0 = blockIdx.x * 128;
  f32x4 acc[4][4] = {};
  for (int k0 = 0; k0 < K; k0 += 64) {
    __syncthreads();
#pragma unroll
    for (int i = 0; i < 4; ++i) {
      int cbase = i * 256 + w * 64;
      int c = cbase + l;
      int r = c >> 3, kc = c & 7;
      const unsigned short* src = A + (size_t)(row0 + r) * Astr + (k0 + kc * 8);
      __builtin_amdgcn_global_load_lds((const as1_void*)src, (as3_void*)&As[cbase * 8], 16, 0, 0);
    }
#pragma unroll
    for (int i = 0; i < 4; ++i) {
      int cbase = i * 256 + w * 64;
      int c = cbase + l;
      int r = c >> 3, kc = c & 7;
      const unsigned short* src = BT + (size_t)(col0 + r) * K + (k0 + kc * 8);
      __builtin_amdgcn_global_load_lds((const as1_void*)src, (as3_void*)&Bs[cbase * 8], 16, 0, 0);
    }
    __syncthreads();
#pragma unroll
    for (int kk = 0; kk < 2; ++kk) {
      bf16x8 af[4], bfr[4];
#pragma unroll
      for (int i = 0; i < 4; ++i)
        af[i] = *(const bf16x8*)&As[(wr * 64 + i * 16 + (l & 15)) * 64 + kk * 32 + (l >> 4) * 8];
#pragma unroll
      for (int j = 0; j < 4; ++j)
        bfr[j] = *(const bf16x8*)&Bs[(wc * 64 + j * 16 + (l & 15)) * 64 + kk * 32 + (l >> 4) * 8];
#pragma unroll
      for (int i = 0; i < 4; ++i)
#pragma unroll
        for (int j = 0; j < 4; ++j)
          acc[i][j] = __builtin_amdgcn_mfma_f32_16x16x32_bf16(af[i], bfr[j], acc[i][j], 0, 0, 0);
    }
  }
#pragma unroll
  for (int i = 0; i < 4; ++i)
#pragma unroll
    for (int j = 0; j < 4; ++j)
#pragma unroll
      for (int t = 0; t < 4; ++t) {
        int r = row0 + wr * 64 + i * 16 + (l >> 4) * 4 + t;
        int c = col0 + wc * 64 + j * 16 + (l & 15);
        float v = acc[i][j][t] + bias[c];
        if (ACT == 1) { if (!(c >= nr_lo && c < nr_hi)) v = fmaxf(v, 0.0f); }
        if (ACT == 2) v = fabsf(v);
        ((unsigned short*)Cp)[(size_t)r * N + c] = f2bfu(v);
      }
}

// ---------------- 256x256 pipelined GEMM (r7-proven schedule), two epilogues -------------
// Snake loop: p0 q(0,0)[lda0,ldb0], p1 q(0,1)[ldb1], p2 q(1,1)[lda1], p3 q(1,0)[ldb0].
// Stage slots into nbuf: p0:A0, p1:B0, p2:B1, p3:A1; WAITV(4) at p0/p1/p3 (p2 none).
// EPI=0: bf16 out, bias + relu except [nr_lo,nr_hi). EPI=1: agent contraction
// (register-hoisted qs/bias, DPP butterfly) -> f32 hid.
template <int EPI>
__global__ __launch_bounds__(512, 2) void gemm256(
    const unsigned short* __restrict__ A, int Astr, const unsigned short* __restrict__ BT,
    const float* __restrict__ bias, const float* __restrict__ qs,
    void* __restrict__ outp, int Cstr, int M, int N, int K, int nr_lo, int nr_hi) {
  __shared__ __align__(16) char smem[131072];  // A: [0,64K) B: [64K,128K); 2 buf x 2 half x 16KB
  const int tid = threadIdx.x;
  const int w = tid >> 6, l = tid & 63;
  const int wrow = w >> 2, wcol = w & 3;
  const int row0 = blockIdx.y * 256, col0 = blockIdx.x * 256;
  const int NT = K >> 6;  // K-tiles; requires K%64==0, NT>=2

  bf16x8 af[8];
  bf16x8 bfr[4];
  f32x4 acc[2][2][4][2] = {};

  auto stage = [&](int mat, int h, int t, int buf) {
    const unsigned short* base = mat ? BT : A;
    const int rbase = (mat ? col0 : row0) + h * 128;
    const int str = mat ? K : Astr;
    const int k0 = t * 64;
    char* region = smem + mat * 65536 + buf * 32768 + h * 16384;
#pragma unroll
    for (int j = 0; j < 2; ++j) {
      const int c = j * 512 + w * 64 + l;
      const int r = c >> 3, kc = c & 7;
      const unsigned short* src =
          base + (size_t)(rbase + r) * str + (k0 + ((kc ^ (r & 7)) << 3));
      __builtin_amdgcn_global_load_lds((const as1_void*)src,
                                       (as3_void*)(region + (j * 512 + w * 64) * 16), 16, 0, 0);
    }
  };
  auto lda = [&](int qa, int buf) {
    const char* region = smem + buf * 32768 + qa * 16384;
#pragma unroll
    for (int i = 0; i < 4; ++i) {
      const int r = wrow * 64 + i * 16 + (l & 15);
#pragma unroll
      for (int kk = 0; kk < 2; ++kk) {
        const int kc = kk * 4 + (l >> 4);
        af[i * 2 + kk] = *(const bf16x8*)(region + r * 128 + ((kc ^ (r & 7)) << 4));
      }
    }
  };
  auto ldb = [&](int qb, int buf) {
    const char* region = smem + 65536 + buf * 32768 + qb * 16384;
#pragma unroll
    for (int j = 0; j < 2; ++j) {
      const int r = wcol * 32 + j * 16 + (l & 15);
#pragma unroll
      for (int kk = 0; kk < 2; ++kk) {
        const int kc = kk * 4 + (l >> 4);
        bfr[j * 2 + kk] = *(const bf16x8*)(region + r * 128 + ((kc ^ (r & 7)) << 4));
      }
    }
  };
  auto mf = [&](f32x4 (&ac)[4][2]) {
    __builtin_amdgcn_s_setprio(1);
#pragma unroll
    for (int i = 0; i < 4; ++i)
#pragma unroll
      for (int j = 0; j < 2; ++j)
#pragma unroll
        for (int kk = 0; kk < 2; ++kk)
          ac[i][j] = __builtin_amdgcn_mfma_f32_16x16x32_bf16(af[i * 2 + kk], bfr[j * 2 + kk],
                                                             ac[i][j], 0, 0, 0);
    __builtin_amdgcn_s_setprio(0);
  };
  auto bar = [&]() {
    asm volatile("" ::: "memory");
    __builtin_amdgcn_s_barrier();
    asm volatile("" ::: "memory");
  };

  // prologue: tile 0 -> buf0 (A0,B0,B1,A1); drain A0,B0
  stage(0, 0, 0, 0); stage(1, 0, 0, 0); stage(1, 1, 0, 0); stage(0, 1, 0, 0);
  WAITV(4);
  bar();

  for (int t = 0; t < NT - 1; ++t) {
    const int buf = t & 1, nbuf = buf ^ 1;
    lda(0, buf); ldb(0, buf);
    stage(0, 0, t + 1, nbuf);
    WAITV(4);
    bar();
    mf(acc[0][0]);
    ldb(1, buf);
    stage(1, 0, t + 1, nbuf);
    WAITV(4);
    bar();
    mf(acc[0][1]);
    lda(1, buf);
    stage(1, 1, t + 1, nbuf);
    bar();
    mf(acc[1][1]);
    ldb(0, buf);
    stage(0, 1, t + 1, nbuf);
    WAITV(4);
    bar();
    mf(acc[1][0]);
  }
  {  // last tile (queue entry: [B1, A1] outstanding)
    const int buf = (NT - 1) & 1;
    lda(0, buf); ldb(0, buf);
    WAITV(2);
    bar();
    mf(acc[0][0]);
    ldb(1, buf);
    WAITV(0);
    bar();
    mf(acc[0][1]);
    lda(1, buf);
    bar();
    mf(acc[1][1]);
    ldb(0, buf);
    bar();
    mf(acc[1][0]);
  }

  if constexpr (EPI == 0) {
#pragma unroll
    for (int qa = 0; qa < 2; ++qa)
#pragma unroll
      for (int qb = 0; qb < 2; ++qb)
#pragma unroll
        for (int i = 0; i < 4; ++i)
#pragma unroll
          for (int j = 0; j < 2; ++j)
#pragma unroll
            for (int tt = 0; tt < 4; ++tt) {
              const int r = row0 + qa * 128 + wrow * 64 + i * 16 + (l >> 4) * 4 + tt;
              const int cc = col0 + qb * 128 + wcol * 32 + j * 16 + (l & 15);
              float v = acc[qa][qb][i][j][tt] + bias[cc];
              if (!(cc >= nr_lo && cc < nr_hi)) v = fmaxf(v, 0.0f);
              ((unsigned short*)outp)[(size_t)r * Cstr + cc] = f2bfu(v);
            }
  } else {
    // agent-contraction epilogue: hoist qs/bias to registers (68 independent loads),
    // then pure VALU + DPP butterfly; write hid[r][e] f32.
    float qv[2][4][4][2];
    float bp[2][2];
#pragma unroll
    for (int qa = 0; qa < 2; ++qa)
#pragma unroll
      for (int i = 0; i < 4; ++i)
#pragma unroll
        for (int tt = 0; tt < 4; ++tt)
#pragma unroll
          for (int j = 0; j < 2; ++j)
            qv[qa][i][tt][j] =
                qs[(size_t)(row0 + qa * 128 + wrow * 64 + i * 16 + (l >> 4) * 4 + tt) * A_DIM +
                   j * 16 + (l & 15)];
#pragma unroll
    for (int qb = 0; qb < 2; ++qb)
#pragma unroll
      for (int j = 0; j < 2; ++j)
        bp[qb][j] = bias[col0 + qb * 128 + wcol * 32 + j * 16 + (l & 15)];
    float* hid = (float*)outp;
#pragma unroll
    for (int qa = 0; qa < 2; ++qa)
#pragma unroll
      for (int qb = 0; qb < 2; ++qb) {
        const int e = (col0 >> 5) + qb * 4 + wcol;
#pragma unroll
        for (int i = 0; i < 4; ++i)
#pragma unroll
          for (int tt = 0; tt < 4; ++tt) {
            const int r = row0 + qa * 128 + wrow * 64 + i * 16 + (l >> 4) * 4 + tt;
            float s = 0.0f;
#pragma unroll
            for (int j = 0; j < 2; ++j)
              s = fmaf(qv[qa][i][tt][j], fabsf(acc[qa][qb][i][j][tt] + bp[qb][j]), s);
            s = row16_sum(s);
            if ((l & 15) == 0) hid[(size_t)r * Cstr + e] = s;
          }
      }
  }
}

// tiny final pass: out[b] = sum_e elu(hid+b1)*wf + sum_e vh*vw2 + vb2
__global__ void final2_kernel(const float* __restrict__ hid, const unsigned short* __restrict__ b1p,
                              const unsigned short* __restrict__ vhp, int ostr,
                              const unsigned short* __restrict__ wf,
                              const float* __restrict__ vw2, const float* __restrict__ vb2,
                              float* __restrict__ out) {
  const int tid = threadIdx.x;  // e
  const int b = blockIdx.x;
  float h = hid[(size_t)b * E_DIM + tid] + bf2f(b1p[(size_t)b * ostr + tid]);
  float hidden = h > 0.0f ? h : (expf(h) - 1.0f);  // elu
  float s = hidden * bf2f(wf[(size_t)b * E_DIM + tid]) +
            bf2f(vhp[(size_t)b * ostr + tid]) * vw2[tid];
  __shared__ float red[4];
#pragma unroll
  for (int o = 32; o > 0; o >>= 1) s += __shfl_down(s, o, 64);
  if ((tid & 63) == 0) red[tid >> 6] = s;
  __syncthreads();
  if (tid == 0) out[b] = red[0] + red[1] + red[2] + red[3] + vb2[0];
}

extern "C" void kernel_launch(void* const* d_in, const int* in_sizes, int n_in,
                              void* d_out, int out_size, void* d_ws, size_t ws_size,
                              hipStream_t stream) {
  const float* agent_qs = (const float*)d_in[0];
  const float* states = (const float*)d_in[1];
  const float* hw1_w1 = (const float*)d_in[2];
  const float* hw1_b1 = (const float*)d_in[3];
  const float* hw1_w2 = (const float*)d_in[4];
  const float* hw1_b2 = (const float*)d_in[5];
  const float* hb1_w = (const float*)d_in[6];
  const float* hb1_b = (const float*)d_in[7];
  const float* hwf_w1 = (const float*)d_in[8];
  const float* hwf_b1 = (const float*)d_in[9];
  const float* hwf_w2 = (const float*)d_in[10];
  const float* hwf_b2 = (const float*)d_in[11];
  const float* v_w1 = (const float*)d_in[12];
  const float* v_b1 = (const float*)d_in[13];
  const float* v_w2 = (const float*)d_in[14];
  const float* v_b2 = (const float*)d_in[15];
  float* out = (float*)d_out;

  size_t off = 0;
  char* ws = (char*)d_ws;
  auto carve = [&](size_t bytes) -> void* {
    void* p = ws + off;
    off = (off + bytes + 255) & ~(size_t)255;
    return p;
  };
  const int NCAT = 2560;  // 1024 h1 | 1024 hf | 256 b1 | 256 vh
  unsigned short* st_bf = (unsigned short*)carve((size_t)B_SZ * S_DIM * 2);
  unsigned short* wcat = (unsigned short*)carve((size_t)NCAT * S_DIM * 2);
  unsigned short* w12T = (unsigned short*)carve((size_t)8192 * H_DIM * 2);
  unsigned short* wf2T = (unsigned short*)carve((size_t)E_DIM * H_DIM * 2);
  float* bcatp = (float*)carve((size_t)NCAT * 4);
  float* bias_p = (float*)carve((size_t)8192 * 4);
  unsigned short* ocat = (unsigned short*)carve((size_t)B_SZ * NCAT * 2);
  unsigned short* wfb = (unsigned short*)carve((size_t)B_SZ * E_DIM * 2);
  float* hid = (float*)carve((size_t)B_SZ * E_DIM * 4);

  // one prep launch: all converts/transposes/bias packs
  prep_kernel<<<PREP_BLOCKS, 256, 0, stream>>>(
      states, hw1_w1, hwf_w1, hb1_w, v_w1, hw1_w2, hwf_w2, hw1_b1, hwf_b1, hb1_b, v_b1,
      hw1_b2, st_bf, wcat, w12T, wf2T, bcatp, bias_p);

  // consolidated K=512 GEMM on the 128-tile path (3 blocks/CU, 5 exact generations):
  // ocat[8192][2560] = relu-except-[2048,2304)(st @ wcat^T + bcat)
  gemm_bt<1><<<dim3(NCAT / 128, B_SZ / 128), 256, 0, stream>>>(
      st_bf, S_DIM, wcat, bcatp, ocat, B_SZ, NCAT, S_DIM, 2048, 2304);

  // w_final = |hf @ hwf_w2 + b|  (A = ocat cols [1024,2048), strided)
  gemm_bt<2><<<dim3(E_DIM / 128, B_SZ / 128), 256, 0, stream>>>(
      ocat + 1024, NCAT, wf2T, hwf_b2, wfb, B_SZ, E_DIM, H_DIM, 0, 0);

  // big GEMM with fused |.| + agent contraction -> hid (A = ocat cols [0,1024), strided)
  gemm256<1><<<dim3(8192 / 256, B_SZ / 256), 512, 0, stream>>>(
      ocat, NCAT, w12T, bias_p, agent_qs, hid, E_DIM, B_SZ, 8192, H_DIM, 0, 0);

  // tiny epilogue
  final2_kernel<<<B_SZ, 256, 0, stream>>>(hid, ocat + 2048, ocat + 2304, NCAT, wfb, v_w2, v_b2, out);
}